// Round 9
// baseline (9998.391 us; speedup 1.0000x reference)
//
#include <hip/hip_runtime.h>
#include <math.h>

#define NROWSQ 32768   // rows per input
#define RTOT   65536   // total rows (mean ++ std)
#define DDIM   512
#define KC     4096

#define CAP2   96            // global candidate list capacity per row
#define WD     1.5e-3f       // dist-unit screen window (covers 2*f16err + ulp)
#define ESCALE 8192.0f       // 2^13, exact
#define EPSC   0.000244140625f   // 2/8192

typedef __attribute__((ext_vector_type(8))) _Float16 half8;
typedef __attribute__((ext_vector_type(4))) float f32x4;

// ---- ws layout (bytes) ----
#define WS_INDS 0               // 65536 * int
#define WS_HIST 262144          // 8192 * int
#define WS_PC1  294912          // 1024 * double
#define WS_PC2  303104          // 1024 * double
#define WS_PKL  311296          // 1024 * double
#define WS_XSQ  319488          // 65536 * float
#define WS_ESQ  581632          // 4096 * float
#define WS_EF16 598016          // 4096*512 u16, TILED
#define WS_EF16_END (598016 + KC * DDIM * 2)

// ---- d_out scratch (overwritten by gather at the end) ----
#define DO_XF16 0               // 65536*512 u16 tiled = 64 MB
#define DO_GCNT 67108864        // 65536 int
#define DO_CAND 67371008        // 65536*96 u16 = 12 MB

__device__ __forceinline__ uint2 pack4_f16(float4 v, float s) {
    _Float16 h0 = (_Float16)(v.x * s);
    _Float16 h1 = (_Float16)(v.y * s);
    _Float16 h2 = (_Float16)(v.z * s);
    _Float16 h3 = (_Float16)(v.w * s);
    uint2 r;
    r.x = (unsigned int)__builtin_bit_cast(unsigned short, h0)
        | ((unsigned int)__builtin_bit_cast(unsigned short, h1) << 16);
    r.y = (unsigned int)__builtin_bit_cast(unsigned short, h2)
        | ((unsigned int)__builtin_bit_cast(unsigned short, h3) << 16);
    return r;
}

__device__ __forceinline__ unsigned fkey(float f) {   // monotone f32->u32
    unsigned u = __float_as_uint(f);
    return u ^ ((unsigned)(((int)u) >> 31) | 0x80000000u);
}
__device__ __forceinline__ float fdecode(unsigned k) {
    return (k & 0x80000000u) ? __uint_as_float(k ^ 0x80000000u) : __uint_as_float(~k);
}

__device__ __forceinline__ void gload_lds16(const void* gsrc, void* ldst) {
    __builtin_amdgcn_global_load_lds(
        (const __attribute__((address_space(1))) unsigned int*)gsrc,
        (__attribute__((address_space(3))) unsigned int*)ldst, 16, 0, 0);
}

__device__ __forceinline__ unsigned long long shfl_xor_u64(unsigned long long v, int off) {
    unsigned lo = (unsigned)v, hi = (unsigned)(v >> 32);
    lo = __shfl_xor(lo, off);
    hi = __shfl_xor(hi, off);
    return ((unsigned long long)hi << 32) | lo;
}

// ---------------------------------------------------------------------------
// Kernel 0: per-row sum of squares (f32), one wave per row.
// ---------------------------------------------------------------------------
__global__ __launch_bounds__(256) void rowsq_kernel(const float* __restrict__ src,
                                                    float* __restrict__ dst,
                                                    int nrows)
{
    int row  = blockIdx.x * 4 + (threadIdx.x >> 6);
    int lane = threadIdx.x & 63;
    if (row >= nrows) return;
    const float* p = src + (size_t)row * DDIM;
    float4 v1 = *(const float4*)&p[lane * 4];
    float4 v2 = *(const float4*)&p[256 + lane * 4];
    float s = v1.x*v1.x + v1.y*v1.y + v1.z*v1.z + v1.w*v1.w
            + v2.x*v2.x + v2.y*v2.y + v2.z*v2.z + v2.w*v2.w;
    #pragma unroll
    for (int off = 1; off < 64; off <<= 1) s += __shfl_xor(s, off);
    if (lane == 0) dst[row] = s;
}

// ---------------------------------------------------------------------------
// Kernel 0b: embedding -> scaled f16, TILED:
// slot(16B) = tile*8192 + chunk*512 + kslot*128 + idx  (chunk=d>>5, kslot=(d>>3)&3)
// ---------------------------------------------------------------------------
__global__ __launch_bounds__(256) void cvt_e_tiled_kernel(const float* __restrict__ emb,
                                                          unsigned short* __restrict__ ef)
{
    int i = blockIdx.x * 256 + threadIdx.x;   // 0..262143
    int c  = i >> 6;
    int dg = i & 63;
    const float* p = &emb[(size_t)c * DDIM + dg * 8];
    float4 v0 = *(const float4*)p;
    float4 v1 = *(const float4*)(p + 4);
    uint2 p0 = pack4_f16(v0, ESCALE);
    uint2 p1 = pack4_f16(v1, ESCALE);
    uint4 pk; pk.x = p0.x; pk.y = p0.y; pk.z = p1.x; pk.w = p1.y;
    size_t slot = (size_t)(c >> 7) * 8192 + (dg >> 2) * 512 + (dg & 3) * 128 + (c & 127);
    *(uint4*)&ef[slot * 8] = pk;
}

// ---------------------------------------------------------------------------
// Kernel 0c: x (mean++std) -> f16 (unscaled), same TILED layout, into d_out.
// ---------------------------------------------------------------------------
__global__ __launch_bounds__(256) void cvt_x_tiled_kernel(const float* __restrict__ xmean,
                                                          const float* __restrict__ xstd,
                                                          unsigned short* __restrict__ xf)
{
    int i = blockIdx.x * 256 + threadIdx.x;   // 0..4194303
    int row = i >> 6;
    int dg  = i & 63;
    const float* X = (row < NROWSQ) ? xmean : xstd;
    int xr = row & (NROWSQ - 1);
    const float* p = &X[(size_t)xr * DDIM + dg * 8];
    float4 v0 = *(const float4*)p;
    float4 v1 = *(const float4*)(p + 4);
    uint2 p0 = pack4_f16(v0, 1.0f);
    uint2 p1 = pack4_f16(v1, 1.0f);
    uint4 pk; pk.x = p0.x; pk.y = p0.y; pk.z = p1.x; pk.w = p1.y;
    size_t slot = (size_t)(row >> 7) * 8192 + (dg >> 2) * 512 + (dg & 3) * 128 + (row & 127);
    *(uint4*)&xf[slot * 8] = pk;
}

// ---------------------------------------------------------------------------
// Pass A: m97-style 128x128 GEMM screen. 16384 blocks (512 rt x 32 ct),
// 256 threads (4 waves, 2x2 grid, 64x64 per wave), BK=64, 33 KB LDS,
// global_load_lds + 2 barriers per K-step, 3 blocks/CU.
// Epilogue: approx dists -> block-local row min -> global candidate append.
// ---------------------------------------------------------------------------
__global__ __launch_bounds__(256, 3) void gemm_screen_kernel(
    const unsigned short* __restrict__ xf, const unsigned short* __restrict__ ef,
    const float* __restrict__ xsq, const float* __restrict__ esq,
    int* __restrict__ gcnt, unsigned short* __restrict__ cand)
{
    __shared__ unsigned short As[8192];   // 16 KB: [kk2][kslot4][row128][8]
    __shared__ unsigned short Bs[8192];   // 16 KB
    __shared__ unsigned int   lmin[128];

    const int t    = threadIdx.x;
    const int lane = t & 63;
    const int wid  = t >> 6;                 // 0..3
    const int wr   = wid >> 1, wc = wid & 1; // wave tile 64 rows x 64 codes
    const int rt   = blockIdx.x >> 5;        // 0..511
    const int ct   = blockIdx.x & 31;        // 0..31

    if (t < 128) lmin[t] = 0xFFFFFFFFu;

    f32x4 acc[4][4];
    #pragma unroll
    for (int fr = 0; fr < 4; ++fr)
        #pragma unroll
        for (int fc = 0; fc < 4; ++fc)
            acc[fr][fc] = (f32x4)(0.0f);

    const unsigned short* ga = xf + (size_t)rt * 8192 * 8;
    const unsigned short* gb = ef + (size_t)ct * 8192 * 8;

    for (int ks = 0; ks < 8; ++ks) {
        __syncthreads();
        #pragma unroll
        for (int s = 0; s < 4; ++s) {
            int slot = s * 256 + t;
            gload_lds16(ga + (size_t)(ks * 1024 + slot) * 8, &As[slot * 8]);
            gload_lds16(gb + (size_t)(ks * 1024 + slot) * 8, &Bs[slot * 8]);
        }
        __syncthreads();
        #pragma unroll
        for (int kk = 0; kk < 2; ++kk) {
            half8 afrag[4], bfrag[4];
            #pragma unroll
            for (int fr = 0; fr < 4; ++fr) {
                int ra  = wr * 64 + fr * 16 + (lane & 15);
                int a16 = kk * 512 + (lane >> 4) * 128 + ra;
                afrag[fr] = *(const half8*)&As[a16 * 8];
            }
            #pragma unroll
            for (int fc = 0; fc < 4; ++fc) {
                int cb  = wc * 64 + fc * 16 + (lane & 15);
                int b16 = kk * 512 + (lane >> 4) * 128 + cb;
                bfrag[fc] = *(const half8*)&Bs[b16 * 8];
            }
            #pragma unroll
            for (int fr = 0; fr < 4; ++fr)
                #pragma unroll
                for (int fc = 0; fc < 4; ++fc)
                    acc[fr][fc] = __builtin_amdgcn_mfma_f32_16x16x32_f16(
                        afrag[fr], bfrag[fc], acc[fr][fc], 0, 0, 0);
        }
    }

    // ---- epilogue: approx dists + block-local row min ----
    float eq[4];
    #pragma unroll
    for (int fc = 0; fc < 4; ++fc)
        eq[fc] = esq[ct * 128 + wc * 64 + fc * 16 + (lane & 15)];

    #pragma unroll
    for (int fr = 0; fr < 4; ++fr) {
        #pragma unroll
        for (int q = 0; q < 4; ++q) {
            int r = wr * 64 + fr * 16 + (lane >> 4) * 4 + q;
            float x2 = xsq[rt * 128 + r];
            float m = INFINITY;
            #pragma unroll
            for (int fc = 0; fc < 4; ++fc) {
                float d = (x2 + eq[fc]) - EPSC * acc[fr][fc][q];
                acc[fr][fc][q] = d;
                m = fminf(m, d);
            }
            unsigned key = fkey(m);
            #pragma unroll
            for (int off = 1; off < 16; off <<= 1) {
                unsigned o = (unsigned)__shfl_xor((int)key, off);
                key = (o < key) ? o : key;
            }
            if ((lane & 15) == 0) atomicMin(&lmin[r], key);
        }
    }
    __syncthreads();

    // ---- append candidates within WD of block-local row min (superset of
    //      the global window restricted to this block: lmin >= gmin) ----
    #pragma unroll
    for (int fr = 0; fr < 4; ++fr) {
        #pragma unroll
        for (int q = 0; q < 4; ++q) {
            int r = wr * 64 + fr * 16 + (lane >> 4) * 4 + q;
            float thr = fdecode(lmin[r]) + WD;
            int gr = rt * 128 + r;
            #pragma unroll
            for (int fc = 0; fc < 4; ++fc) {
                if (acc[fr][fc][q] <= thr) {
                    int code = ct * 128 + wc * 64 + fc * 16 + (lane & 15);
                    int p = atomicAdd(&gcnt[gr], 1);
                    if (p < CAP2) cand[(size_t)gr * CAP2 + p] = (unsigned short)code;
                }
            }
        }
    }
}

// ---------------------------------------------------------------------------
// Pass B: exact f32 rescore, one wave per row (round-1-identical fmaf chain).
// ---------------------------------------------------------------------------
__global__ __launch_bounds__(512) void rescore_kernel(
    const float* __restrict__ xmean, const float* __restrict__ xstd,
    const float* __restrict__ emb,
    const float* __restrict__ xsq, const float* __restrict__ esq,
    const int* __restrict__ gcnt, const unsigned short* __restrict__ cand,
    int* __restrict__ inds)
{
    const int wave = threadIdx.x >> 6, lane = threadIdx.x & 63;
    const int r = blockIdx.x * 8 + wave;
    const float* X = (r < NROWSQ) ? xmean : xstd;
    const float* xp = X + (size_t)(r & (NROWSQ - 1)) * DDIM;
    const float x2 = xsq[r];
    const int cnt = gcnt[r];

    unsigned long long best = ~0ull;
    if (cnt <= CAP2) {
        for (int k = lane; k < cnt; k += 64) {
            int c = cand[(size_t)r * CAP2 + k];
            const float* ep = emb + (size_t)c * DDIM;
            float acc2 = 0.0f;
            for (int d = 0; d < DDIM; d += 4) {
                float4 xv = *(const float4*)&xp[d];
                float4 ev = *(const float4*)&ep[d];
                acc2 = fmaf(xv.x, ev.x, acc2);
                acc2 = fmaf(xv.y, ev.y, acc2);
                acc2 = fmaf(xv.z, ev.z, acc2);
                acc2 = fmaf(xv.w, ev.w, acc2);
            }
            float dist = (x2 + esq[c]) - 2.0f * acc2;
            unsigned long long key =
                ((unsigned long long)__float_as_uint(dist) << 32) | (unsigned)c;
            if (key < best) best = key;
        }
    } else {
        for (int c = lane; c < KC; c += 64) {
            const float* ep = emb + (size_t)c * DDIM;
            float acc2 = 0.0f;
            #pragma unroll 8
            for (int d = 0; d < DDIM; d += 4) {
                float4 xv = *(const float4*)&xp[d];
                float4 ev = *(const float4*)&ep[d];
                acc2 = fmaf(xv.x, ev.x, acc2);
                acc2 = fmaf(xv.y, ev.y, acc2);
                acc2 = fmaf(xv.z, ev.z, acc2);
                acc2 = fmaf(xv.w, ev.w, acc2);
            }
            float dist = (x2 + esq[c]) - 2.0f * acc2;
            unsigned long long key =
                ((unsigned long long)__float_as_uint(dist) << 32) | (unsigned)c;
            if (key < best) best = key;
        }
    }
    #pragma unroll
    for (int off = 1; off < 64; off <<= 1) {
        unsigned long long o = shfl_xor_u64(best, off);
        if (o < best) best = o;
    }
    if (lane == 0) inds[r] = (int)(unsigned)(best & 0xffffffffull);
}

// ---------------------------------------------------------------------------
// Fallback argmin (ws too small for ef16): round-7 structure, f32 B loads.
// ---------------------------------------------------------------------------
__global__ __launch_bounds__(512, 1) void argmin_fallback_kernel(
    const float* __restrict__ xmean, const float* __restrict__ xstd,
    const float* __restrict__ emb,
    const float* __restrict__ xsq, const float* __restrict__ esq,
    int* __restrict__ inds)
{
    __shared__ unsigned short As[65536];
    __shared__ unsigned int   rowmax[128];
    __shared__ int            ccnt[128];
    __shared__ unsigned short cnd[128 * 32];
    __shared__ unsigned long long best[128];

    const int t    = threadIdx.x;
    const int lane = t & 63;
    const int wid  = t >> 6;
    const int wr   = wid >> 2, wc = wid & 3;
    const int row0 = blockIdx.x * 128;
    const float* X = (row0 < NROWSQ) ? xmean : xstd;
    const int xrow0 = (row0 < NROWSQ) ? row0 : row0 - NROWSQ;

    if (t < 128) { rowmax[t] = 0u; ccnt[t] = 0; best[t] = ~0ull; }

    #pragma unroll 4
    for (int s = 0; s < 16; ++s) {
        int i   = t + s * 512;
        int dg  = i & 63;
        int row = i >> 6;
        const float* xp = &X[(size_t)(xrow0 + row) * DDIM + dg * 8];
        float4 v0 = *(const float4*)xp;
        float4 v1 = *(const float4*)(xp + 4);
        uint2 p0 = pack4_f16(v0, 1.0f);
        uint2 p1 = pack4_f16(v1, 1.0f);
        uint4 pk; pk.x = p0.x; pk.y = p0.y; pk.z = p1.x; pk.w = p1.y;
        int a16 = dg * 128 + (row ^ (dg & 7));
        *(uint4*)&As[a16 * 8] = pk;
    }
    __syncthreads();

    for (int ctile = 0; ctile < 32; ++ctile) {
        f32x4 acc[4][2];
        #pragma unroll
        for (int fr = 0; fr < 4; ++fr)
            #pragma unroll
            for (int fc = 0; fc < 2; ++fc)
                acc[fr][fc] = (f32x4)(0.0f);

        #pragma unroll 2
        for (int c = 0; c < 16; ++c) {
            half8 bfrag[2], afrag[4];
            #pragma unroll
            for (int fc = 0; fc < 2; ++fc) {
                int code = ctile * 128 + wc * 32 + fc * 16 + (lane & 15);
                const float* p = &emb[(size_t)code * DDIM + c * 32 + (lane >> 4) * 8];
                float4 v0 = *(const float4*)p;
                float4 v1 = *(const float4*)(p + 4);
                uint2 p0 = pack4_f16(v0, ESCALE);
                uint2 p1 = pack4_f16(v1, ESCALE);
                uint4 pk; pk.x = p0.x; pk.y = p0.y; pk.z = p1.x; pk.w = p1.y;
                bfrag[fc] = __builtin_bit_cast(half8, pk);
            }
            #pragma unroll
            for (int fr = 0; fr < 4; ++fr) {
                int ra = wr * 64 + fr * 16 + (lane & 15);
                int dg = c * 4 + (lane >> 4);
                int a16 = dg * 128 + (ra ^ (dg & 7));
                afrag[fr] = *(const half8*)&As[a16 * 8];
            }
            #pragma unroll
            for (int fr = 0; fr < 4; ++fr)
                #pragma unroll
                for (int fc = 0; fc < 2; ++fc)
                    acc[fr][fc] = __builtin_amdgcn_mfma_f32_16x16x32_f16(
                        afrag[fr], bfrag[fc], acc[fr][fc], 0, 0, 0);
        }

        #pragma unroll
        for (int fr = 0; fr < 4; ++fr)
            #pragma unroll
            for (int q = 0; q < 4; ++q) {
                float m = fmaxf(acc[fr][0][q], acc[fr][1][q]);
                int r = wr * 64 + fr * 16 + (lane >> 4) * 4 + q;
                unsigned k = fkey(m);
                if (k > rowmax[r]) atomicMax(&rowmax[r], k);
            }
        __syncthreads();
        #pragma unroll
        for (int fr = 0; fr < 4; ++fr)
            #pragma unroll
            for (int q = 0; q < 4; ++q) {
                int r = wr * 64 + fr * 16 + (lane >> 4) * 4 + q;
                float thr = fdecode(rowmax[r]) - 6.0f;
                #pragma unroll
                for (int fc = 0; fc < 2; ++fc)
                    if (acc[fr][fc][q] >= thr) {
                        int code = ctile * 128 + wc * 32 + fc * 16 + (lane & 15);
                        int p = atomicAdd(&ccnt[r], 1);
                        if (p < 32) cnd[r * 32 + p] = (unsigned short)code;
                    }
            }
    }
    __syncthreads();

    for (int e = t; e < 128 * 32; e += 512) {
        int r = e >> 5, s = e & 31;
        int cnt = ccnt[r]; if (cnt > 32) cnt = 32;
        if (s < cnt) {
            int c = cnd[r * 32 + s];
            const float* xp = X + (size_t)(xrow0 + r) * DDIM;
            const float* ep = emb + (size_t)c * DDIM;
            float acc2 = 0.0f;
            for (int d = 0; d < DDIM; d += 4) {
                float4 xv = *(const float4*)&xp[d];
                float4 ev = *(const float4*)&ep[d];
                acc2 = fmaf(xv.x, ev.x, acc2);
                acc2 = fmaf(xv.y, ev.y, acc2);
                acc2 = fmaf(xv.z, ev.z, acc2);
                acc2 = fmaf(xv.w, ev.w, acc2);
            }
            float dist = (xsq[row0 + r] + esq[c]) - 2.0f * acc2;
            unsigned long long key =
                ((unsigned long long)__float_as_uint(dist) << 32) | (unsigned)c;
            atomicMin(&best[r], key);
        }
    }
    __syncthreads();
    for (int r = 0; r < 128; ++r) {
        if (ccnt[r] > 32) {
            const float* xp = X + (size_t)(xrow0 + r) * DDIM;
            float xse = xsq[row0 + r];
            for (int c = t; c < KC; c += 512) {
                const float* ep = emb + (size_t)c * DDIM;
                float acc2 = 0.0f;
                #pragma unroll 8
                for (int d = 0; d < DDIM; d += 4) {
                    float4 xv = *(const float4*)&xp[d];
                    float4 ev = *(const float4*)&ep[d];
                    acc2 = fmaf(xv.x, ev.x, acc2);
                    acc2 = fmaf(xv.y, ev.y, acc2);
                    acc2 = fmaf(xv.z, ev.z, acc2);
                    acc2 = fmaf(xv.w, ev.w, acc2);
                }
                float dist = (xse + esq[c]) - 2.0f * acc2;
                unsigned long long key =
                    ((unsigned long long)__float_as_uint(dist) << 32) | (unsigned)c;
                atomicMin(&best[r], key);
            }
        }
    }
    __syncthreads();
    if (t < 128) inds[row0 + t] = (int)(unsigned)(best[t] & 0xffffffffull);
}

// ---------------------------------------------------------------------------
// Kernel 2: gather quantized rows + commitment/KL partials + hist. (unchanged)
// ---------------------------------------------------------------------------
__global__ __launch_bounds__(256) void gather_stats_kernel(
    const float* __restrict__ xmean, const float* __restrict__ xstd,
    const float* __restrict__ emb, const int* __restrict__ inds,
    float* __restrict__ out0, float* __restrict__ out1,
    int* __restrict__ hist,
    double* __restrict__ pc1, double* __restrict__ pc2, double* __restrict__ pkl)
{
    const int blk  = blockIdx.x;
    const int w    = threadIdx.x >> 6;
    const int lane = threadIdx.x & 63;

    float c1 = 0.0f, c2 = 0.0f, kls = 0.0f;

    for (int j = 0; j < 8; j++) {
        int n  = blk * 32 + j * 4 + w;
        int im = inds[n];
        int is = inds[NROWSQ + n];
        if (lane == 0) {
            atomicAdd(&hist[im], 1);
            atomicAdd(&hist[KC + is], 1);
        }
        const float* em = emb  + (size_t)im * DDIM;
        const float* es = emb  + (size_t)is * DDIM;
        const float* xm = xmean + (size_t)n * DDIM;
        const float* xv = xstd  + (size_t)n * DDIM;

        float t1 = 0.0f, t2 = 0.0f;
        float pp = 1.0f, pq = 1.0f;

        #pragma unroll
        for (int half = 0; half < 2; half++) {
            int d = half * 256 + lane * 4;
            float4 q4  = *(const float4*)&em[d];
            float4 m4  = *(const float4*)&xm[d];
            float4 qs4 = *(const float4*)&es[d];
            float4 s4  = *(const float4*)&xv[d];
            float qa[4] = {q4.x, q4.y, q4.z, q4.w};
            float ma[4] = {m4.x, m4.y, m4.z, m4.w};
            float qb[4] = {qs4.x, qs4.y, qs4.z, qs4.w};
            float sa[4] = {s4.x, s4.y, s4.z, s4.w};
            float o0[4], o1[4];
            #pragma unroll
            for (int u = 0; u < 4; u++) {
                float q = qa[u], m = ma[u], s = sa[u], qq = qb[u];
                o0[u] = m + (q - m);
                o1[u] = qq;
                float du = q - m;
                c1 += du * du;
                float dsv = qq - s; c2 += dsv * dsv;
                float sp = s * s, sq = qq * qq;
                float iq = 1.0f / sq;
                t1 += sp * iq;
                t2 += du * du * iq;
                pp *= sp; pq *= sq;
            }
            *(float4*)&out0[(size_t)n * DDIM + d] = make_float4(o0[0], o0[1], o0[2], o0[3]);
            *(float4*)&out1[(size_t)n * DDIM + d] = make_float4(o1[0], o1[1], o1[2], o1[3]);
        }

        #pragma unroll
        for (int off = 1; off < 64; off <<= 1) {
            t1 += __shfl_xor(t1, off);
            t2 += __shfl_xor(t2, off);
            pp *= __shfl_xor(pp, off);
            pq *= __shfl_xor(pq, off);
        }
        if (lane == 0) {
            float term4 = logf(pq + 1e-8f) - logf(pp + 1e-8f);
            float kl = 0.5f * (t1 + t2 - (float)DDIM + term4);
            float klc = kl < 0.0f ? 0.0f : (kl > 10.0f ? 10.0f : kl);
            kls += klc;
        }
    }

    #pragma unroll
    for (int off = 1; off < 64; off <<= 1) {
        c1 += __shfl_xor(c1, off);
        c2 += __shfl_xor(c2, off);
    }
    __shared__ double sc1[4], sc2[4], skl[4];
    if (lane == 0) { sc1[w] = (double)c1; sc2[w] = (double)c2; skl[w] = (double)kls; }
    __syncthreads();
    if (threadIdx.x == 0) {
        pc1[blk] = sc1[0] + sc1[1] + sc1[2] + sc1[3];
        pc2[blk] = sc2[0] + sc2[1] + sc2[2] + sc2[3];
        pkl[blk] = skl[0] + skl[1] + skl[2] + skl[3];
    }
}

// ---------------------------------------------------------------------------
// Kernel 3: finalize scalars. (unchanged)
// ---------------------------------------------------------------------------
__global__ __launch_bounds__(256) void finalize_kernel(
    const int* __restrict__ hist,
    const double* __restrict__ pc1, const double* __restrict__ pc2,
    const double* __restrict__ pkl,
    float* __restrict__ out)
{
    int t = threadIdx.x;
    int w = t >> 6, lane = t & 63;

    double a = 0.0, b = 0.0, c = 0.0;
    for (int i = t; i < 1024; i += 256) { a += pc1[i]; b += pc2[i]; c += pkl[i]; }

    float hm = 0.0f, hs = 0.0f;
    for (int k = t; k < KC; k += 256) {
        float p  = (float)hist[k]      * (1.0f / 32768.0f);
        hm += p * logf(p + 1e-10f);
        float p2 = (float)hist[KC + k] * (1.0f / 32768.0f);
        hs += p2 * logf(p2 + 1e-10f);
    }

    #pragma unroll
    for (int off = 1; off < 64; off <<= 1) {
        a  += __shfl_xor(a, off);
        b  += __shfl_xor(b, off);
        c  += __shfl_xor(c, off);
        hm += __shfl_xor(hm, off);
        hs += __shfl_xor(hs, off);
    }
    __shared__ double sa[4], sb[4], sc[4];
    __shared__ float  sm[4], ss[4];
    if (lane == 0) { sa[w] = a; sb[w] = b; sc[w] = c; sm[w] = hm; ss[w] = hs; }
    __syncthreads();
    if (t == 0) {
        double A = sa[0] + sa[1] + sa[2] + sa[3];
        double B = sb[0] + sb[1] + sb[2] + sb[3];
        double C = sc[0] + sc[1] + sc[2] + sc[3];
        float HM = sm[0] + sm[1] + sm[2] + sm[3];
        float HS = ss[0] + ss[1] + ss[2] + ss[3];
        float mean1 = (float)(A * (1.0 / 16777216.0));
        float mean2 = (float)(B * (1.0 / 16777216.0));
        float commitment = mean1 + mean2;
        float el = (float)(C * (1.0 / 32768.0));
        out[33554432] = commitment * 0.25f + el;   // vq_loss
        out[33554433] = expf(-HM);                 // perplexity_mean
        out[33554434] = expf(-HS);                 // perplexity_std
    }
}

// ---------------------------------------------------------------------------
extern "C" void kernel_launch(void* const* d_in, const int* in_sizes, int n_in,
                              void* d_out, int out_size, void* d_ws, size_t ws_size,
                              hipStream_t stream)
{
    const float* xmean = (const float*)d_in[0];
    const float* xstd  = (const float*)d_in[1];
    const float* emb   = (const float*)d_in[2];
    float* out = (float*)d_out;
    char*  ws  = (char*)d_ws;
    char*  ob  = (char*)d_out;

    int*    inds = (int*)(ws + WS_INDS);
    int*    hist = (int*)(ws + WS_HIST);
    double* pc1  = (double*)(ws + WS_PC1);
    double* pc2  = (double*)(ws + WS_PC2);
    double* pkl  = (double*)(ws + WS_PKL);
    float*  xsq  = (float*)(ws + WS_XSQ);
    float*  esq  = (float*)(ws + WS_ESQ);
    unsigned short* ef16 = (unsigned short*)(ws + WS_EF16);

    unsigned short* xf16 = (unsigned short*)(ob + DO_XF16);
    int*            gcnt = (int*)(ob + DO_GCNT);
    unsigned short* cand = (unsigned short*)(ob + DO_CAND);

    const bool fast = (ws_size >= (size_t)WS_EF16_END);

    hipMemsetAsync(hist, 0, 2 * KC * sizeof(int), stream);

    rowsq_kernel<<<NROWSQ / 4, 256, 0, stream>>>(xmean, xsq, NROWSQ);
    rowsq_kernel<<<NROWSQ / 4, 256, 0, stream>>>(xstd, xsq + NROWSQ, NROWSQ);
    rowsq_kernel<<<KC / 4, 256, 0, stream>>>(emb, esq, KC);

    if (fast) {
        hipMemsetAsync(gcnt, 0, RTOT * sizeof(int), stream);
        cvt_e_tiled_kernel<<<1024, 256, 0, stream>>>(emb, ef16);
        cvt_x_tiled_kernel<<<16384, 256, 0, stream>>>(xmean, xstd, xf16);
        gemm_screen_kernel<<<16384, 256, 0, stream>>>(xf16, ef16, xsq, esq, gcnt, cand);
        rescore_kernel<<<RTOT / 8, 512, 0, stream>>>(xmean, xstd, emb, xsq, esq,
                                                     gcnt, cand, inds);
    } else {
        argmin_fallback_kernel<<<RTOT / 128, 512, 0, stream>>>(
            xmean, xstd, emb, xsq, esq, inds);
    }

    gather_stats_kernel<<<1024, 256, 0, stream>>>(xmean, xstd, emb, inds,
                                                  out, out + (size_t)NROWSQ * DDIM,
                                                  hist, pc1, pc2, pkl);

    finalize_kernel<<<1, 256, 0, stream>>>(hist, pc1, pc2, pkl, out);
}

// Round 10
// 1106.265 us; speedup vs baseline: 9.0380x; 9.0380x over previous
//
#include <hip/hip_runtime.h>
#include <math.h>

#define NROWSQ 32768   // rows per input
#define RTOT   65536   // total rows (mean ++ std)
#define DDIM   512
#define KC     4096

#define CAP    48          // candidate list capacity per row
#define W_ACC  6.0f        // screen window in acc units (dist window = 6/4096)
#define ESCALE 8192.0f     // 2^13, exact

typedef __attribute__((ext_vector_type(8))) _Float16 half8;
typedef __attribute__((ext_vector_type(4))) float f32x4;

// ---- ws layout (bytes) ----
#define WS_INDS 0               // 65536 * int
#define WS_HIST 262144          // 8192 * int
#define WS_PC1  294912          // 1024 * double
#define WS_PC2  303104          // 1024 * double
#define WS_PKL  311296          // 1024 * double
#define WS_XSQ  319488          // 65536 * float
#define WS_ESQ  581632          // 4096 * float
#define WS_EF16 598016          // 4096*512 u16, TILED
#define WS_EF16_END (598016 + KC * DDIM * 2)

__device__ __forceinline__ uint2 pack4_f16(float4 v, float s) {
    _Float16 h0 = (_Float16)(v.x * s);
    _Float16 h1 = (_Float16)(v.y * s);
    _Float16 h2 = (_Float16)(v.z * s);
    _Float16 h3 = (_Float16)(v.w * s);
    uint2 r;
    r.x = (unsigned int)__builtin_bit_cast(unsigned short, h0)
        | ((unsigned int)__builtin_bit_cast(unsigned short, h1) << 16);
    r.y = (unsigned int)__builtin_bit_cast(unsigned short, h2)
        | ((unsigned int)__builtin_bit_cast(unsigned short, h3) << 16);
    return r;
}

__device__ __forceinline__ unsigned fkey(float f) {   // monotone f32->u32
    unsigned u = __float_as_uint(f);
    return u ^ ((unsigned)(((int)u) >> 31) | 0x80000000u);
}
__device__ __forceinline__ float fdecode(unsigned k) {
    return (k & 0x80000000u) ? __uint_as_float(k ^ 0x80000000u) : __uint_as_float(~k);
}

// ---------------------------------------------------------------------------
// Kernel 0: per-row sum of squares (f32), one wave per row.
// ---------------------------------------------------------------------------
__global__ __launch_bounds__(256) void rowsq_kernel(const float* __restrict__ src,
                                                    float* __restrict__ dst,
                                                    int nrows)
{
    int row  = blockIdx.x * 4 + (threadIdx.x >> 6);
    int lane = threadIdx.x & 63;
    if (row >= nrows) return;
    const float* p = src + (size_t)row * DDIM;
    float4 v1 = *(const float4*)&p[lane * 4];
    float4 v2 = *(const float4*)&p[256 + lane * 4];
    float s = v1.x*v1.x + v1.y*v1.y + v1.z*v1.z + v1.w*v1.w
            + v2.x*v2.x + v2.y*v2.y + v2.z*v2.z + v2.w*v2.w;
    #pragma unroll
    for (int off = 1; off < 64; off <<= 1) s += __shfl_xor(s, off);
    if (lane == 0) dst[row] = s;
}

// ---------------------------------------------------------------------------
// Kernel 0b: embedding -> scaled f16, TILED:
// slot(16B) = (c>>7)*8192 + (d>>5)*512 + ((d>>3)&3)*128 + (c&127)
// ---------------------------------------------------------------------------
__global__ __launch_bounds__(256) void cvt_e_tiled_kernel(const float* __restrict__ emb,
                                                          unsigned short* __restrict__ ef)
{
    int i = blockIdx.x * 256 + threadIdx.x;   // 0..262143
    int c  = i >> 6;
    int dg = i & 63;
    const float* p = &emb[(size_t)c * DDIM + dg * 8];
    float4 v0 = *(const float4*)p;
    float4 v1 = *(const float4*)(p + 4);
    uint2 p0 = pack4_f16(v0, ESCALE);
    uint2 p1 = pack4_f16(v1, ESCALE);
    uint4 pk; pk.x = p0.x; pk.y = p0.y; pk.z = p1.x; pk.w = p1.y;
    size_t slot = (size_t)(c >> 7) * 8192 + (dg >> 2) * 512 + (dg & 3) * 128 + (c & 127);
    *(uint4*)&ef[slot * 8] = pk;
}

// ---------------------------------------------------------------------------
// Kernel 1: 64-row A-stripe in LDS, 8 waves x 512 codes each, B direct
// global->VGPR from L2-resident tiled ef16. No barriers in the hot loop.
// Delayed append with f16-dist-tagged candidates + final prune vs final
// row max, then exact in-block f32 rescore (bit-identical inds).
// ---------------------------------------------------------------------------
template<bool EF16>
__global__ __launch_bounds__(512, 4) void mfma_argmin_v2_kernel(
    const float* __restrict__ xmean, const float* __restrict__ xstd,
    const float* __restrict__ emb, const unsigned short* __restrict__ ef,
    const float* __restrict__ xsq, const float* __restrict__ esq,
    int* __restrict__ inds)
{
    __shared__ unsigned short As[64 * 512];   // 64 KB, dg-major, XOR-swz
    __shared__ unsigned int   rowmax[64];
    __shared__ int            ccnt[64];
    __shared__ unsigned int   cand[64 * CAP]; // (f16(acc)<<16) | code
    __shared__ unsigned long long best[64];

    const int t    = threadIdx.x;
    const int lane = t & 63;
    const int wid  = t >> 6;                  // 0..7: wave owns 512 codes
    const int row0 = blockIdx.x * 64;
    const float* X = (row0 < NROWSQ) ? xmean : xstd;
    const int xrow0 = row0 & (NROWSQ - 1);

    if (t < 64) { rowmax[t] = 0u; ccnt[t] = 0; best[t] = ~0ull; }

    // ---- stage A once: 64 rows x 512 d, f32 -> f16, swizzled ----
    #pragma unroll
    for (int s2 = 0; s2 < 8; ++s2) {
        int i   = t + s2 * 512;      // 0..4095 (16B slots)
        int dg  = i & 63;
        int row = i >> 6;
        const float* xp = &X[(size_t)(xrow0 + row) * DDIM + dg * 8];
        float4 v0 = *(const float4*)xp;
        float4 v1 = *(const float4*)(xp + 4);
        uint2 p0 = pack4_f16(v0, 1.0f);
        uint2 p1 = pack4_f16(v1, 1.0f);
        uint4 pk; pk.x = p0.x; pk.y = p0.y; pk.z = p1.x; pk.w = p1.y;
        int a16 = dg * 64 + (row ^ (dg & 7));
        *(uint4*)&As[a16 * 8] = pk;
    }
    __syncthreads();

    const uint4* __restrict__ bptr = (const uint4*)ef;

    // ---- per-chunk compute: 32 codes x 64 rows over full K=512 ----
    auto COMPUTE = [&](int s, f32x4 (&acc)[4][2]) {
        #pragma unroll
        for (int fr = 0; fr < 4; ++fr)
            #pragma unroll
            for (int fc = 0; fc < 2; ++fc)
                acc[fr][fc] = (f32x4)(0.0f);

        const int ct = wid * 4 + (s >> 2);
        const int co = (s & 3) * 32;
        const size_t bbase = (size_t)ct * 8192 + (size_t)((lane >> 4) * 128 + co + (lane & 15));

        #pragma unroll
        for (int k = 0; k < 16; ++k) {
            half8 bf0, bf1;
            if (EF16) {
                bf0 = __builtin_bit_cast(half8, bptr[bbase + k * 512]);
                bf1 = __builtin_bit_cast(half8, bptr[bbase + k * 512 + 16]);
            } else {
                #pragma unroll
                for (int fc = 0; fc < 2; ++fc) {
                    int code = wid * 512 + s * 32 + fc * 16 + (lane & 15);
                    const float* p = &emb[(size_t)code * DDIM + k * 32 + (lane >> 4) * 8];
                    float4 v0 = *(const float4*)p;
                    float4 v1 = *(const float4*)(p + 4);
                    uint2 q0 = pack4_f16(v0, ESCALE);
                    uint2 q1 = pack4_f16(v1, ESCALE);
                    uint4 pk; pk.x = q0.x; pk.y = q0.y; pk.z = q1.x; pk.w = q1.y;
                    if (fc == 0) bf0 = __builtin_bit_cast(half8, pk);
                    else         bf1 = __builtin_bit_cast(half8, pk);
                }
            }
            half8 af[4];
            #pragma unroll
            for (int fr = 0; fr < 4; ++fr) {
                int dg  = k * 4 + (lane >> 4);
                int a16 = dg * 64 + ((fr * 16 + (lane & 15)) ^ (dg & 7));
                af[fr] = *(const half8*)&As[a16 * 8];
            }
            #pragma unroll
            for (int fr = 0; fr < 4; ++fr) {
                acc[fr][0] = __builtin_amdgcn_mfma_f32_16x16x32_f16(af[fr], bf0, acc[fr][0], 0, 0, 0);
                acc[fr][1] = __builtin_amdgcn_mfma_f32_16x16x32_f16(af[fr], bf1, acc[fr][1], 0, 0, 0);
            }
        }

        // shared running row-max (16-lane shuffle reduce, 1 atomic per row)
        #pragma unroll
        for (int fr = 0; fr < 4; ++fr) {
            #pragma unroll
            for (int q = 0; q < 4; ++q) {
                float m = fmaxf(acc[fr][0][q], acc[fr][1][q]);
                #pragma unroll
                for (int off = 1; off < 16; off <<= 1)
                    m = fmaxf(m, __shfl_xor(m, off));
                if ((lane & 15) == 0) {
                    int r = fr * 16 + (lane >> 4) * 4 + q;
                    unsigned k2 = fkey(m);
                    if (k2 > rowmax[r]) atomicMax(&rowmax[r], k2);
                }
            }
        }
    };

    auto APPEND = [&](int s, f32x4 (&acc)[4][2]) {
        const int cb = wid * 512 + s * 32;
        #pragma unroll
        for (int fr = 0; fr < 4; ++fr) {
            #pragma unroll
            for (int q = 0; q < 4; ++q) {
                int r = fr * 16 + (lane >> 4) * 4 + q;
                float thr = fdecode(rowmax[r]) - W_ACC;
                #pragma unroll
                for (int fc = 0; fc < 2; ++fc) {
                    if (acc[fr][fc][q] >= thr) {
                        int code = cb + fc * 16 + (lane & 15);
                        int p = atomicAdd(&ccnt[r], 1);
                        if (p < CAP) {
                            _Float16 h = (_Float16)acc[fr][fc][q];
                            cand[r * CAP + p] =
                                ((unsigned)__builtin_bit_cast(unsigned short, h) << 16)
                                | (unsigned)code;
                        }
                    }
                }
            }
        }
    };

    f32x4 accA[4][2], accB[4][2];
    COMPUTE(0, accA);
    #pragma unroll 1
    for (int s = 1; s < 16; s += 2) {
        COMPUTE(s, accB);
        APPEND(s - 1, accA);
        if (s + 1 < 16) COMPUTE(s + 1, accA);
        APPEND(s, accB);
    }
    __syncthreads();   // rowmax now FINAL (block covers all 4096 codes)

    // ---- prune (vs final max) + exact f32 rescore (round-1 fmaf chain) ----
    for (int e = t; e < 64 * CAP; e += 512) {
        int r = e / CAP, sidx = e - r * CAP;
        int cnt = ccnt[r]; if (cnt > CAP) cnt = CAP;
        if (sidx < cnt) {
            unsigned ent = cand[r * CAP + sidx];
            float av = (float)__builtin_bit_cast(_Float16, (unsigned short)(ent >> 16));
            float fin = fdecode(rowmax[r]);
            if (av >= fin - W_ACC - 1.0f) {     // 1.0 = f16 storage slop
                int c = (int)(ent & 0xFFFFu);
                const float* xp = X   + (size_t)(xrow0 + r) * DDIM;
                const float* ep = emb + (size_t)c * DDIM;
                float acc2 = 0.0f;
                for (int d = 0; d < DDIM; d += 4) {
                    float4 xv = *(const float4*)&xp[d];
                    float4 ev = *(const float4*)&ep[d];
                    acc2 = fmaf(xv.x, ev.x, acc2);
                    acc2 = fmaf(xv.y, ev.y, acc2);
                    acc2 = fmaf(xv.z, ev.z, acc2);
                    acc2 = fmaf(xv.w, ev.w, acc2);
                }
                float dist = (xsq[row0 + r] + esq[c]) - 2.0f * acc2;
                unsigned long long key =
                    ((unsigned long long)__float_as_uint(dist) << 32) | (unsigned)c;
                atomicMin(&best[r], key);
            }
        }
    }
    __syncthreads();

    // ---- overflow fallback: full-row exact rescan (expected: ~never) ----
    for (int r = 0; r < 64; ++r) {
        if (ccnt[r] > CAP) {
            const float* xp = X + (size_t)(xrow0 + r) * DDIM;
            float xse = xsq[row0 + r];
            for (int c = t; c < KC; c += 512) {
                const float* ep = emb + (size_t)c * DDIM;
                float acc2 = 0.0f;
                #pragma unroll 8
                for (int d = 0; d < DDIM; d += 4) {
                    float4 xv = *(const float4*)&xp[d];
                    float4 ev = *(const float4*)&ep[d];
                    acc2 = fmaf(xv.x, ev.x, acc2);
                    acc2 = fmaf(xv.y, ev.y, acc2);
                    acc2 = fmaf(xv.z, ev.z, acc2);
                    acc2 = fmaf(xv.w, ev.w, acc2);
                }
                float dist = (xse + esq[c]) - 2.0f * acc2;
                unsigned long long key =
                    ((unsigned long long)__float_as_uint(dist) << 32) | (unsigned)c;
                atomicMin(&best[r], key);
            }
        }
    }
    __syncthreads();
    if (t < 64) inds[row0 + t] = (int)(unsigned)(best[t] & 0xffffffffull);
}

// ---------------------------------------------------------------------------
// Kernel 2: gather quantized rows + commitment/KL partials + hist. (unchanged)
// ---------------------------------------------------------------------------
__global__ __launch_bounds__(256) void gather_stats_kernel(
    const float* __restrict__ xmean, const float* __restrict__ xstd,
    const float* __restrict__ emb, const int* __restrict__ inds,
    float* __restrict__ out0, float* __restrict__ out1,
    int* __restrict__ hist,
    double* __restrict__ pc1, double* __restrict__ pc2, double* __restrict__ pkl)
{
    const int blk  = blockIdx.x;
    const int w    = threadIdx.x >> 6;
    const int lane = threadIdx.x & 63;

    float c1 = 0.0f, c2 = 0.0f, kls = 0.0f;

    for (int j = 0; j < 8; j++) {
        int n  = blk * 32 + j * 4 + w;
        int im = inds[n];
        int is = inds[NROWSQ + n];
        if (lane == 0) {
            atomicAdd(&hist[im], 1);
            atomicAdd(&hist[KC + is], 1);
        }
        const float* em = emb  + (size_t)im * DDIM;
        const float* es = emb  + (size_t)is * DDIM;
        const float* xm = xmean + (size_t)n * DDIM;
        const float* xv = xstd  + (size_t)n * DDIM;

        float t1 = 0.0f, t2 = 0.0f;
        float pp = 1.0f, pq = 1.0f;

        #pragma unroll
        for (int half = 0; half < 2; half++) {
            int d = half * 256 + lane * 4;
            float4 q4  = *(const float4*)&em[d];
            float4 m4  = *(const float4*)&xm[d];
            float4 qs4 = *(const float4*)&es[d];
            float4 s4  = *(const float4*)&xv[d];
            float qa[4] = {q4.x, q4.y, q4.z, q4.w};
            float ma[4] = {m4.x, m4.y, m4.z, m4.w};
            float qb[4] = {qs4.x, qs4.y, qs4.z, qs4.w};
            float sa[4] = {s4.x, s4.y, s4.z, s4.w};
            float o0[4], o1[4];
            #pragma unroll
            for (int u = 0; u < 4; u++) {
                float q = qa[u], m = ma[u], s = sa[u], qq = qb[u];
                o0[u] = m + (q - m);
                o1[u] = qq;
                float du = q - m;
                c1 += du * du;
                float dsv = qq - s; c2 += dsv * dsv;
                float sp = s * s, sq = qq * qq;
                float iq = 1.0f / sq;
                t1 += sp * iq;
                t2 += du * du * iq;
                pp *= sp; pq *= sq;
            }
            *(float4*)&out0[(size_t)n * DDIM + d] = make_float4(o0[0], o0[1], o0[2], o0[3]);
            *(float4*)&out1[(size_t)n * DDIM + d] = make_float4(o1[0], o1[1], o1[2], o1[3]);
        }

        #pragma unroll
        for (int off = 1; off < 64; off <<= 1) {
            t1 += __shfl_xor(t1, off);
            t2 += __shfl_xor(t2, off);
            pp *= __shfl_xor(pp, off);
            pq *= __shfl_xor(pq, off);
        }
        if (lane == 0) {
            float term4 = logf(pq + 1e-8f) - logf(pp + 1e-8f);
            float kl = 0.5f * (t1 + t2 - (float)DDIM + term4);
            float klc = kl < 0.0f ? 0.0f : (kl > 10.0f ? 10.0f : kl);
            kls += klc;
        }
    }

    #pragma unroll
    for (int off = 1; off < 64; off <<= 1) {
        c1 += __shfl_xor(c1, off);
        c2 += __shfl_xor(c2, off);
    }
    __shared__ double sc1[4], sc2[4], skl[4];
    if (lane == 0) { sc1[w] = (double)c1; sc2[w] = (double)c2; skl[w] = (double)kls; }
    __syncthreads();
    if (threadIdx.x == 0) {
        pc1[blk] = sc1[0] + sc1[1] + sc1[2] + sc1[3];
        pc2[blk] = sc2[0] + sc2[1] + sc2[2] + sc2[3];
        pkl[blk] = skl[0] + skl[1] + skl[2] + skl[3];
    }
}

// ---------------------------------------------------------------------------
// Kernel 3: finalize scalars. (unchanged)
// ---------------------------------------------------------------------------
__global__ __launch_bounds__(256) void finalize_kernel(
    const int* __restrict__ hist,
    const double* __restrict__ pc1, const double* __restrict__ pc2,
    const double* __restrict__ pkl,
    float* __restrict__ out)
{
    int t = threadIdx.x;
    int w = t >> 6, lane = t & 63;

    double a = 0.0, b = 0.0, c = 0.0;
    for (int i = t; i < 1024; i += 256) { a += pc1[i]; b += pc2[i]; c += pkl[i]; }

    float hm = 0.0f, hs = 0.0f;
    for (int k = t; k < KC; k += 256) {
        float p  = (float)hist[k]      * (1.0f / 32768.0f);
        hm += p * logf(p + 1e-10f);
        float p2 = (float)hist[KC + k] * (1.0f / 32768.0f);
        hs += p2 * logf(p2 + 1e-10f);
    }

    #pragma unroll
    for (int off = 1; off < 64; off <<= 1) {
        a  += __shfl_xor(a, off);
        b  += __shfl_xor(b, off);
        c  += __shfl_xor(c, off);
        hm += __shfl_xor(hm, off);
        hs += __shfl_xor(hs, off);
    }
    __shared__ double sa[4], sb[4], sc[4];
    __shared__ float  sm[4], ss[4];
    if (lane == 0) { sa[w] = a; sb[w] = b; sc[w] = c; sm[w] = hm; ss[w] = hs; }
    __syncthreads();
    if (t == 0) {
        double A = sa[0] + sa[1] + sa[2] + sa[3];
        double B = sb[0] + sb[1] + sb[2] + sb[3];
        double C = sc[0] + sc[1] + sc[2] + sc[3];
        float HM = sm[0] + sm[1] + sm[2] + sm[3];
        float HS = ss[0] + ss[1] + ss[2] + ss[3];
        float mean1 = (float)(A * (1.0 / 16777216.0));
        float mean2 = (float)(B * (1.0 / 16777216.0));
        float commitment = mean1 + mean2;
        float el = (float)(C * (1.0 / 32768.0));
        out[33554432] = commitment * 0.25f + el;   // vq_loss
        out[33554433] = expf(-HM);                 // perplexity_mean
        out[33554434] = expf(-HS);                 // perplexity_std
    }
}

// ---------------------------------------------------------------------------
extern "C" void kernel_launch(void* const* d_in, const int* in_sizes, int n_in,
                              void* d_out, int out_size, void* d_ws, size_t ws_size,
                              hipStream_t stream)
{
    const float* xmean = (const float*)d_in[0];
    const float* xstd  = (const float*)d_in[1];
    const float* emb   = (const float*)d_in[2];
    float* out = (float*)d_out;
    char*  ws  = (char*)d_ws;

    int*    inds = (int*)(ws + WS_INDS);
    int*    hist = (int*)(ws + WS_HIST);
    double* pc1  = (double*)(ws + WS_PC1);
    double* pc2  = (double*)(ws + WS_PC2);
    double* pkl  = (double*)(ws + WS_PKL);
    float*  xsq  = (float*)(ws + WS_XSQ);
    float*  esq  = (float*)(ws + WS_ESQ);
    unsigned short* ef16 = (unsigned short*)(ws + WS_EF16);

    const bool fast = (ws_size >= (size_t)WS_EF16_END);

    hipMemsetAsync(hist, 0, 2 * KC * sizeof(int), stream);

    rowsq_kernel<<<NROWSQ / 4, 256, 0, stream>>>(xmean, xsq, NROWSQ);
    rowsq_kernel<<<NROWSQ / 4, 256, 0, stream>>>(xstd, xsq + NROWSQ, NROWSQ);
    rowsq_kernel<<<KC / 4, 256, 0, stream>>>(emb, esq, KC);

    if (fast) {
        cvt_e_tiled_kernel<<<1024, 256, 0, stream>>>(emb, ef16);
        mfma_argmin_v2_kernel<true><<<RTOT / 64, 512, 0, stream>>>(
            xmean, xstd, emb, ef16, xsq, esq, inds);
    } else {
        mfma_argmin_v2_kernel<false><<<RTOT / 64, 512, 0, stream>>>(
            xmean, xstd, emb, ef16, xsq, esq, inds);
    }

    gather_stats_kernel<<<1024, 256, 0, stream>>>(xmean, xstd, emb, inds,
                                                  out, out + (size_t)NROWSQ * DDIM,
                                                  hist, pc1, pc2, pkl);

    finalize_kernel<<<1, 256, 0, stream>>>(hist, pc1, pc2, pkl, out);
}

// Round 11
// 921.671 us; speedup vs baseline: 10.8481x; 1.2003x over previous
//
#include <hip/hip_runtime.h>
#include <math.h>

#define NROWSQ 32768   // rows per input
#define RTOT   65536   // total rows (mean ++ std)
#define DDIM   512
#define KC     4096

#define CAP    56          // candidate list capacity per row
#define W_ACC  6.0f        // screen window in acc units (dist window = 6/4096)
#define ESCALE 8192.0f     // 2^13, exact

typedef __attribute__((ext_vector_type(8))) _Float16 half8;
typedef __attribute__((ext_vector_type(4))) float f32x4;

// ---- ws layout (bytes) ----
#define WS_INDS 0               // 65536 * int
#define WS_HIST 262144          // 8192 * int
#define WS_PC1  294912          // 1024 * double
#define WS_PC2  303104          // 1024 * double
#define WS_PKL  311296          // 1024 * double
#define WS_XSQ  319488          // 65536 * float
#define WS_ESQ  581632          // 4096 * float
#define WS_EF16 598016          // 4096*512 u16, TILED
#define WS_EF16_END (598016 + KC * DDIM * 2)

__device__ __forceinline__ uint2 pack4_f16(float4 v, float s) {
    _Float16 h0 = (_Float16)(v.x * s);
    _Float16 h1 = (_Float16)(v.y * s);
    _Float16 h2 = (_Float16)(v.z * s);
    _Float16 h3 = (_Float16)(v.w * s);
    uint2 r;
    r.x = (unsigned int)__builtin_bit_cast(unsigned short, h0)
        | ((unsigned int)__builtin_bit_cast(unsigned short, h1) << 16);
    r.y = (unsigned int)__builtin_bit_cast(unsigned short, h2)
        | ((unsigned int)__builtin_bit_cast(unsigned short, h3) << 16);
    return r;
}

__device__ __forceinline__ unsigned fkey(float f) {   // monotone f32->u32
    unsigned u = __float_as_uint(f);
    return u ^ ((unsigned)(((int)u) >> 31) | 0x80000000u);
}
__device__ __forceinline__ float fdecode(unsigned k) {
    return (k & 0x80000000u) ? __uint_as_float(k ^ 0x80000000u) : __uint_as_float(~k);
}

// ---------------------------------------------------------------------------
// Kernel 0: per-row sum of squares (f32), one wave per row.
// ---------------------------------------------------------------------------
__global__ __launch_bounds__(256) void rowsq_kernel(const float* __restrict__ src,
                                                    float* __restrict__ dst,
                                                    int nrows)
{
    int row  = blockIdx.x * 4 + (threadIdx.x >> 6);
    int lane = threadIdx.x & 63;
    if (row >= nrows) return;
    const float* p = src + (size_t)row * DDIM;
    float4 v1 = *(const float4*)&p[lane * 4];
    float4 v2 = *(const float4*)&p[256 + lane * 4];
    float s = v1.x*v1.x + v1.y*v1.y + v1.z*v1.z + v1.w*v1.w
            + v2.x*v2.x + v2.y*v2.y + v2.z*v2.z + v2.w*v2.w;
    #pragma unroll
    for (int off = 1; off < 64; off <<= 1) s += __shfl_xor(s, off);
    if (lane == 0) dst[row] = s;
}

// ---------------------------------------------------------------------------
// Kernel 0b: embedding -> scaled f16, TILED:
// slot(16B) = (c>>7)*8192 + (d>>5)*512 + ((d>>3)&3)*128 + (c&127)
// ---------------------------------------------------------------------------
__global__ __launch_bounds__(256) void cvt_e_tiled_kernel(const float* __restrict__ emb,
                                                          unsigned short* __restrict__ ef)
{
    int i = blockIdx.x * 256 + threadIdx.x;   // 0..262143
    int c  = i >> 6;
    int dg = i & 63;
    const float* p = &emb[(size_t)c * DDIM + dg * 8];
    float4 v0 = *(const float4*)p;
    float4 v1 = *(const float4*)(p + 4);
    uint2 p0 = pack4_f16(v0, ESCALE);
    uint2 p1 = pack4_f16(v1, ESCALE);
    uint4 pk; pk.x = p0.x; pk.y = p0.y; pk.z = p1.x; pk.w = p1.y;
    size_t slot = (size_t)(c >> 7) * 8192 + (dg >> 2) * 512 + (dg & 3) * 128 + (c & 127);
    *(uint4*)&ef[slot * 8] = pk;
}

// ---------------------------------------------------------------------------
// Kernel 1: 64-row A-stripe in LDS, 8 waves x 512 codes each, B direct
// global->VGPR from L2-resident tiled ef16. No barriers in the hot loop.
// IMMEDIATE append with f16-dist-tagged candidates (single acc set -> no
// spills) + final prune vs final row max, then exact in-block f32 rescore.
// ---------------------------------------------------------------------------
template<bool EF16>
__global__ __launch_bounds__(512, 4) void mfma_argmin_v2_kernel(
    const float* __restrict__ xmean, const float* __restrict__ xstd,
    const float* __restrict__ emb, const unsigned short* __restrict__ ef,
    const float* __restrict__ xsq, const float* __restrict__ esq,
    int* __restrict__ inds)
{
    __shared__ unsigned short As[64 * 512];   // 64 KB, dg-major, XOR-swz
    __shared__ unsigned int   rowmax[64];
    __shared__ int            ccnt[64];
    __shared__ unsigned int   cand[64 * CAP]; // (f16(acc)<<16) | code
    __shared__ unsigned long long best[64];

    const int t    = threadIdx.x;
    const int lane = t & 63;
    const int wid  = t >> 6;                  // 0..7: wave owns 512 codes
    const int row0 = blockIdx.x * 64;
    const float* X = (row0 < NROWSQ) ? xmean : xstd;
    const int xrow0 = row0 & (NROWSQ - 1);

    if (t < 64) { rowmax[t] = 0u; ccnt[t] = 0; best[t] = ~0ull; }

    // ---- stage A once: 64 rows x 512 d, f32 -> f16, swizzled ----
    #pragma unroll
    for (int s2 = 0; s2 < 8; ++s2) {
        int i   = t + s2 * 512;      // 0..4095 (16B slots)
        int dg  = i & 63;
        int row = i >> 6;
        const float* xp = &X[(size_t)(xrow0 + row) * DDIM + dg * 8];
        float4 v0 = *(const float4*)xp;
        float4 v1 = *(const float4*)(xp + 4);
        uint2 p0 = pack4_f16(v0, 1.0f);
        uint2 p1 = pack4_f16(v1, 1.0f);
        uint4 pk; pk.x = p0.x; pk.y = p0.y; pk.z = p1.x; pk.w = p1.y;
        int a16 = dg * 64 + (row ^ (dg & 7));
        *(uint4*)&As[a16 * 8] = pk;
    }
    __syncthreads();

    const uint4* __restrict__ bptr = (const uint4*)ef;

    // ---- 16 chunks of 32 codes x 64 rows over full K=512 ----
    #pragma unroll 1
    for (int s = 0; s < 16; ++s) {
        f32x4 acc[4][2];
        #pragma unroll
        for (int fr = 0; fr < 4; ++fr)
            #pragma unroll
            for (int fc = 0; fc < 2; ++fc)
                acc[fr][fc] = (f32x4)(0.0f);

        const int ct = wid * 4 + (s >> 2);
        const int co = (s & 3) * 32;
        const size_t bbase = (size_t)ct * 8192 + (size_t)((lane >> 4) * 128 + co + (lane & 15));

        #pragma unroll
        for (int k = 0; k < 16; ++k) {
            half8 bf0, bf1;
            if (EF16) {
                bf0 = __builtin_bit_cast(half8, bptr[bbase + k * 512]);
                bf1 = __builtin_bit_cast(half8, bptr[bbase + k * 512 + 16]);
            } else {
                #pragma unroll
                for (int fc = 0; fc < 2; ++fc) {
                    int code = wid * 512 + s * 32 + fc * 16 + (lane & 15);
                    const float* p = &emb[(size_t)code * DDIM + k * 32 + (lane >> 4) * 8];
                    float4 v0 = *(const float4*)p;
                    float4 v1 = *(const float4*)(p + 4);
                    uint2 q0 = pack4_f16(v0, ESCALE);
                    uint2 q1 = pack4_f16(v1, ESCALE);
                    uint4 pk; pk.x = q0.x; pk.y = q0.y; pk.z = q1.x; pk.w = q1.y;
                    if (fc == 0) bf0 = __builtin_bit_cast(half8, pk);
                    else         bf1 = __builtin_bit_cast(half8, pk);
                }
            }
            half8 af[4];
            #pragma unroll
            for (int fr = 0; fr < 4; ++fr) {
                int dg  = k * 4 + (lane >> 4);
                int a16 = dg * 64 + ((fr * 16 + (lane & 15)) ^ (dg & 7));
                af[fr] = *(const half8*)&As[a16 * 8];
            }
            #pragma unroll
            for (int fr = 0; fr < 4; ++fr) {
                acc[fr][0] = __builtin_amdgcn_mfma_f32_16x16x32_f16(af[fr], bf0, acc[fr][0], 0, 0, 0);
                acc[fr][1] = __builtin_amdgcn_mfma_f32_16x16x32_f16(af[fr], bf1, acc[fr][1], 0, 0, 0);
            }
        }

        // ---- update shared running row-max (16-lane reduce, 1 atomic/row) ----
        #pragma unroll
        for (int fr = 0; fr < 4; ++fr) {
            #pragma unroll
            for (int q = 0; q < 4; ++q) {
                float m = fmaxf(acc[fr][0][q], acc[fr][1][q]);
                #pragma unroll
                for (int off = 1; off < 16; off <<= 1)
                    m = fmaxf(m, __shfl_xor(m, off));
                if ((lane & 15) == 0) {
                    int r = fr * 16 + (lane >> 4) * 4 + q;
                    unsigned k2 = fkey(m);
                    if (k2 > rowmax[r]) atomicMax(&rowmax[r], k2);
                }
            }
        }

        // ---- immediate append vs current running max (superset; final
        //      prune below filters against the final max) ----
        const int cb = wid * 512 + s * 32;
        #pragma unroll
        for (int fr = 0; fr < 4; ++fr) {
            #pragma unroll
            for (int q = 0; q < 4; ++q) {
                int r = fr * 16 + (lane >> 4) * 4 + q;
                float thr = fdecode(rowmax[r]) - W_ACC;
                #pragma unroll
                for (int fc = 0; fc < 2; ++fc) {
                    if (acc[fr][fc][q] >= thr) {
                        int code = cb + fc * 16 + (lane & 15);
                        int p = atomicAdd(&ccnt[r], 1);
                        if (p < CAP) {
                            _Float16 h = (_Float16)acc[fr][fc][q];
                            cand[r * CAP + p] =
                                ((unsigned)__builtin_bit_cast(unsigned short, h) << 16)
                                | (unsigned)code;
                        }
                    }
                }
            }
        }
    }
    __syncthreads();   // rowmax now FINAL (block covers all 4096 codes)

    // ---- prune (vs final max) + exact f32 rescore (round-1 fmaf chain) ----
    for (int e = t; e < 64 * CAP; e += 512) {
        int r = e / CAP, sidx = e - r * CAP;
        int cnt = ccnt[r]; if (cnt > CAP) cnt = CAP;
        if (sidx < cnt) {
            unsigned ent = cand[r * CAP + sidx];
            float av = (float)__builtin_bit_cast(_Float16, (unsigned short)(ent >> 16));
            float fin = fdecode(rowmax[r]);
            if (av >= fin - W_ACC - 1.0f) {     // 1.0 = f16 storage slop
                int c = (int)(ent & 0xFFFFu);
                const float* xp = X   + (size_t)(xrow0 + r) * DDIM;
                const float* ep = emb + (size_t)c * DDIM;
                float acc2 = 0.0f;
                for (int d = 0; d < DDIM; d += 4) {
                    float4 xv = *(const float4*)&xp[d];
                    float4 ev = *(const float4*)&ep[d];
                    acc2 = fmaf(xv.x, ev.x, acc2);
                    acc2 = fmaf(xv.y, ev.y, acc2);
                    acc2 = fmaf(xv.z, ev.z, acc2);
                    acc2 = fmaf(xv.w, ev.w, acc2);
                }
                float dist = (xsq[row0 + r] + esq[c]) - 2.0f * acc2;
                unsigned long long key =
                    ((unsigned long long)__float_as_uint(dist) << 32) | (unsigned)c;
                atomicMin(&best[r], key);
            }
        }
    }
    __syncthreads();

    // ---- overflow fallback: full-row exact rescan (expected: ~never) ----
    for (int r = 0; r < 64; ++r) {
        if (ccnt[r] > CAP) {
            const float* xp = X + (size_t)(xrow0 + r) * DDIM;
            float xse = xsq[row0 + r];
            for (int c = t; c < KC; c += 512) {
                const float* ep = emb + (size_t)c * DDIM;
                float acc2 = 0.0f;
                #pragma unroll 8
                for (int d = 0; d < DDIM; d += 4) {
                    float4 xv = *(const float4*)&xp[d];
                    float4 ev = *(const float4*)&ep[d];
                    acc2 = fmaf(xv.x, ev.x, acc2);
                    acc2 = fmaf(xv.y, ev.y, acc2);
                    acc2 = fmaf(xv.z, ev.z, acc2);
                    acc2 = fmaf(xv.w, ev.w, acc2);
                }
                float dist = (xse + esq[c]) - 2.0f * acc2;
                unsigned long long key =
                    ((unsigned long long)__float_as_uint(dist) << 32) | (unsigned)c;
                atomicMin(&best[r], key);
            }
        }
    }
    __syncthreads();
    if (t < 64) inds[row0 + t] = (int)(unsigned)(best[t] & 0xffffffffull);
}

// ---------------------------------------------------------------------------
// Kernel 2: gather quantized rows + commitment/KL partials + hist. (unchanged)
// ---------------------------------------------------------------------------
__global__ __launch_bounds__(256) void gather_stats_kernel(
    const float* __restrict__ xmean, const float* __restrict__ xstd,
    const float* __restrict__ emb, const int* __restrict__ inds,
    float* __restrict__ out0, float* __restrict__ out1,
    int* __restrict__ hist,
    double* __restrict__ pc1, double* __restrict__ pc2, double* __restrict__ pkl)
{
    const int blk  = blockIdx.x;
    const int w    = threadIdx.x >> 6;
    const int lane = threadIdx.x & 63;

    float c1 = 0.0f, c2 = 0.0f, kls = 0.0f;

    for (int j = 0; j < 8; j++) {
        int n  = blk * 32 + j * 4 + w;
        int im = inds[n];
        int is = inds[NROWSQ + n];
        if (lane == 0) {
            atomicAdd(&hist[im], 1);
            atomicAdd(&hist[KC + is], 1);
        }
        const float* em = emb  + (size_t)im * DDIM;
        const float* es = emb  + (size_t)is * DDIM;
        const float* xm = xmean + (size_t)n * DDIM;
        const float* xv = xstd  + (size_t)n * DDIM;

        float t1 = 0.0f, t2 = 0.0f;
        float pp = 1.0f, pq = 1.0f;

        #pragma unroll
        for (int half = 0; half < 2; half++) {
            int d = half * 256 + lane * 4;
            float4 q4  = *(const float4*)&em[d];
            float4 m4  = *(const float4*)&xm[d];
            float4 qs4 = *(const float4*)&es[d];
            float4 s4  = *(const float4*)&xv[d];
            float qa[4] = {q4.x, q4.y, q4.z, q4.w};
            float ma[4] = {m4.x, m4.y, m4.z, m4.w};
            float qb[4] = {qs4.x, qs4.y, qs4.z, qs4.w};
            float sa[4] = {s4.x, s4.y, s4.z, s4.w};
            float o0[4], o1[4];
            #pragma unroll
            for (int u = 0; u < 4; u++) {
                float q = qa[u], m = ma[u], s = sa[u], qq = qb[u];
                o0[u] = m + (q - m);
                o1[u] = qq;
                float du = q - m;
                c1 += du * du;
                float dsv = qq - s; c2 += dsv * dsv;
                float sp = s * s, sq = qq * qq;
                float iq = 1.0f / sq;
                t1 += sp * iq;
                t2 += du * du * iq;
                pp *= sp; pq *= sq;
            }
            *(float4*)&out0[(size_t)n * DDIM + d] = make_float4(o0[0], o0[1], o0[2], o0[3]);
            *(float4*)&out1[(size_t)n * DDIM + d] = make_float4(o1[0], o1[1], o1[2], o1[3]);
        }

        #pragma unroll
        for (int off = 1; off < 64; off <<= 1) {
            t1 += __shfl_xor(t1, off);
            t2 += __shfl_xor(t2, off);
            pp *= __shfl_xor(pp, off);
            pq *= __shfl_xor(pq, off);
        }
        if (lane == 0) {
            float term4 = logf(pq + 1e-8f) - logf(pp + 1e-8f);
            float kl = 0.5f * (t1 + t2 - (float)DDIM + term4);
            float klc = kl < 0.0f ? 0.0f : (kl > 10.0f ? 10.0f : kl);
            kls += klc;
        }
    }

    #pragma unroll
    for (int off = 1; off < 64; off <<= 1) {
        c1 += __shfl_xor(c1, off);
        c2 += __shfl_xor(c2, off);
    }
    __shared__ double sc1[4], sc2[4], skl[4];
    if (lane == 0) { sc1[w] = (double)c1; sc2[w] = (double)c2; skl[w] = (double)kls; }
    __syncthreads();
    if (threadIdx.x == 0) {
        pc1[blk] = sc1[0] + sc1[1] + sc1[2] + sc1[3];
        pc2[blk] = sc2[0] + sc2[1] + sc2[2] + sc2[3];
        pkl[blk] = skl[0] + skl[1] + skl[2] + skl[3];
    }
}

// ---------------------------------------------------------------------------
// Kernel 3: finalize scalars. (unchanged)
// ---------------------------------------------------------------------------
__global__ __launch_bounds__(256) void finalize_kernel(
    const int* __restrict__ hist,
    const double* __restrict__ pc1, const double* __restrict__ pc2,
    const double* __restrict__ pkl,
    float* __restrict__ out)
{
    int t = threadIdx.x;
    int w = t >> 6, lane = t & 63;

    double a = 0.0, b = 0.0, c = 0.0;
    for (int i = t; i < 1024; i += 256) { a += pc1[i]; b += pc2[i]; c += pkl[i]; }

    float hm = 0.0f, hs = 0.0f;
    for (int k = t; k < KC; k += 256) {
        float p  = (float)hist[k]      * (1.0f / 32768.0f);
        hm += p * logf(p + 1e-10f);
        float p2 = (float)hist[KC + k] * (1.0f / 32768.0f);
        hs += p2 * logf(p2 + 1e-10f);
    }

    #pragma unroll
    for (int off = 1; off < 64; off <<= 1) {
        a  += __shfl_xor(a, off);
        b  += __shfl_xor(b, off);
        c  += __shfl_xor(c, off);
        hm += __shfl_xor(hm, off);
        hs += __shfl_xor(hs, off);
    }
    __shared__ double sa[4], sb[4], sc[4];
    __shared__ float  sm[4], ss[4];
    if (lane == 0) { sa[w] = a; sb[w] = b; sc[w] = c; sm[w] = hm; ss[w] = hs; }
    __syncthreads();
    if (t == 0) {
        double A = sa[0] + sa[1] + sa[2] + sa[3];
        double B = sb[0] + sb[1] + sb[2] + sb[3];
        double C = sc[0] + sc[1] + sc[2] + sc[3];
        float HM = sm[0] + sm[1] + sm[2] + sm[3];
        float HS = ss[0] + ss[1] + ss[2] + ss[3];
        float mean1 = (float)(A * (1.0 / 16777216.0));
        float mean2 = (float)(B * (1.0 / 16777216.0));
        float commitment = mean1 + mean2;
        float el = (float)(C * (1.0 / 32768.0));
        out[33554432] = commitment * 0.25f + el;   // vq_loss
        out[33554433] = expf(-HM);                 // perplexity_mean
        out[33554434] = expf(-HS);                 // perplexity_std
    }
}

// ---------------------------------------------------------------------------
extern "C" void kernel_launch(void* const* d_in, const int* in_sizes, int n_in,
                              void* d_out, int out_size, void* d_ws, size_t ws_size,
                              hipStream_t stream)
{
    const float* xmean = (const float*)d_in[0];
    const float* xstd  = (const float*)d_in[1];
    const float* emb   = (const float*)d_in[2];
    float* out = (float*)d_out;
    char*  ws  = (char*)d_ws;

    int*    inds = (int*)(ws + WS_INDS);
    int*    hist = (int*)(ws + WS_HIST);
    double* pc1  = (double*)(ws + WS_PC1);
    double* pc2  = (double*)(ws + WS_PC2);
    double* pkl  = (double*)(ws + WS_PKL);
    float*  xsq  = (float*)(ws + WS_XSQ);
    float*  esq  = (float*)(ws + WS_ESQ);
    unsigned short* ef16 = (unsigned short*)(ws + WS_EF16);

    const bool fast = (ws_size >= (size_t)WS_EF16_END);

    hipMemsetAsync(hist, 0, 2 * KC * sizeof(int), stream);

    rowsq_kernel<<<NROWSQ / 4, 256, 0, stream>>>(xmean, xsq, NROWSQ);
    rowsq_kernel<<<NROWSQ / 4, 256, 0, stream>>>(xstd, xsq + NROWSQ, NROWSQ);
    rowsq_kernel<<<KC / 4, 256, 0, stream>>>(emb, esq, KC);

    if (fast) {
        cvt_e_tiled_kernel<<<1024, 256, 0, stream>>>(emb, ef16);
        mfma_argmin_v2_kernel<true><<<RTOT / 64, 512, 0, stream>>>(
            xmean, xstd, emb, ef16, xsq, esq, inds);
    } else {
        mfma_argmin_v2_kernel<false><<<RTOT / 64, 512, 0, stream>>>(
            xmean, xstd, emb, ef16, xsq, esq, inds);
    }

    gather_stats_kernel<<<1024, 256, 0, stream>>>(xmean, xstd, emb, inds,
                                                  out, out + (size_t)NROWSQ * DDIM,
                                                  hist, pc1, pc2, pkl);

    finalize_kernel<<<1, 256, 0, stream>>>(hist, pc1, pc2, pkl, out);
}